// Round 1
// baseline (1046.402 us; speedup 1.0000x reference)
//
#include <hip/hip_runtime.h>
#include <stdint.h>

#define NROWS 500000
#define NCLS 100
#define NBINS 15
#define CHUNK 15625   // 500000 / 32 blocks-per-class

// rank targets: f_0 = 0 (min), f_b = floor(b * float32(500000/15)) for b=1..14
__device__ __forceinline__ int rank_target(int b) {
    if (b == 0) return 0;
    const float step = 500000.0f / 15.0f;   // float32-rounded, mimics jnp.linspace
    return (int)floorf((float)b * step);
}

__device__ __forceinline__ float wave_sum(float v) {
    #pragma unroll
    for (int o = 32; o; o >>= 1) v += __shfl_xor(v, o, 64);
    return v;
}

// Pass 1: row softmax of logits [N][C], write transposed probsT [C][N]
__global__ __launch_bounds__(256) void k_softmax_t(const float* __restrict__ logits,
                                                   float* __restrict__ probsT) {
    __shared__ float tile[64][101];   // +1 pad breaks bank conflicts
    __shared__ float red[256];
    __shared__ float mx[64];
    __shared__ float inv[64];
    const int row0 = blockIdx.x * 64;
    const int rows = min(64, NROWS - row0);
    const int t = threadIdx.x;
    const int total = rows * NCLS;
    for (int k = t; k < total; k += 256) {
        int r = k / NCLS, c = k - r * NCLS;
        tile[r][c] = logits[(size_t)(row0 + r) * NCLS + c];
    }
    __syncthreads();
    const int r = t >> 2, q = t & 3;   // 4 threads per row
    if (r < rows) {
        float m = -1e30f;
        for (int c = q * 25; c < q * 25 + 25; ++c) m = fmaxf(m, tile[r][c]);
        red[t] = m;
    }
    __syncthreads();
    if (r < rows && q == 0)
        mx[r] = fmaxf(fmaxf(red[t], red[t + 1]), fmaxf(red[t + 2], red[t + 3]));
    __syncthreads();
    if (r < rows) {
        float m = mx[r], s = 0.f;
        for (int c = q * 25; c < q * 25 + 25; ++c) {
            float e = expf(tile[r][c] - m);
            tile[r][c] = e;
            s += e;
        }
        red[t] = s;
    }
    __syncthreads();
    if (r < rows && q == 0)
        inv[r] = 1.0f / (red[t] + red[t + 1] + red[t + 2] + red[t + 3]);
    __syncthreads();
    for (int k = t; k < NCLS * 64; k += 256) {
        int c = k >> 6, rr = k & 63;
        if (rr < rows)
            probsT[(size_t)c * NROWS + row0 + rr] = tile[rr][c] * inv[rr];
    }
}

// Pass 2: per-class L1 histogram on top 12 used bits of the float pattern
__global__ __launch_bounds__(256) void k_hist1(const float* __restrict__ probsT,
                                               int* __restrict__ hist1) {
    __shared__ int h[4096];
    const int c = blockIdx.y, t = threadIdx.x;
    for (int i = t; i < 4096; i += 256) h[i] = 0;
    __syncthreads();
    const size_t base = (size_t)c * NROWS;
    const int start = blockIdx.x * CHUNK;
    const int end = min(NROWS, start + CHUNK);
    for (int i = start + t; i < end; i += 256) {
        unsigned bits = __float_as_uint(probsT[base + i]);
        atomicAdd(&h[bits >> 18], 1);
    }
    __syncthreads();
    for (int i = t; i < 4096; i += 256) {
        int v = h[i];
        if (v) atomicAdd(&hist1[c * 4096 + i], v);
    }
}

// Select L1 bucket containing each rank target
__global__ __launch_bounds__(256) void k_sel1(const int* __restrict__ hist1,
                                              int* __restrict__ tgt,
                                              int* __restrict__ below) {
    __shared__ int part[256];
    const int c = blockIdx.x, t = threadIdx.x;
    int loc[16], s = 0;
    #pragma unroll
    for (int i = 0; i < 16; ++i) { loc[i] = hist1[c * 4096 + t * 16 + i]; s += loc[i]; }
    part[t] = s;
    __syncthreads();
    if (t == 0) {
        int run = 0;
        for (int i = 0; i < 256; ++i) { int v = part[i]; part[i] = run; run += v; }
    }
    __syncthreads();
    const int cum0 = part[t];
    for (int b = 0; b < NBINS; ++b) {
        const int f = rank_target(b);
        int cc = cum0;
        #pragma unroll
        for (int i = 0; i < 16; ++i) {
            if (f >= cc && f < cc + loc[i]) {
                tgt[c * NBINS + b] = t * 16 + i;
                below[c * NBINS + b] = cc;
            }
            cc += loc[i];
        }
    }
}

// Pass 3: refine — histogram bits 6..17 of elements inside each target bucket
__global__ __launch_bounds__(256) void k_hist2(const float* __restrict__ probsT,
                                               const int* __restrict__ tgt,
                                               int* __restrict__ hist2) {
    const int c = blockIdx.y, t = threadIdx.x;
    int tg[NBINS];
    #pragma unroll
    for (int b = 0; b < NBINS; ++b) tg[b] = tgt[c * NBINS + b];
    const size_t base = (size_t)c * NROWS;
    const int start = blockIdx.x * CHUNK;
    const int end = min(NROWS, start + CHUNK);
    for (int i = start + t; i < end; i += 256) {
        unsigned bits = __float_as_uint(probsT[base + i]);
        int k1 = bits >> 18;
        int sub = (bits >> 6) & 0xFFF;
        #pragma unroll
        for (int b = 0; b < NBINS; ++b)
            if (k1 == tg[b])
                atomicAdd(&hist2[((size_t)c * NBINS + b) * 4096 + sub], 1);
    }
}

// Select sub-bucket; boundary = top float of the 64-ULP sub-bucket holding the rank
__global__ __launch_bounds__(256) void k_sel2(const int* __restrict__ hist2,
                                              const int* __restrict__ tgt,
                                              const int* __restrict__ below,
                                              float* __restrict__ bounds) {
    __shared__ int part[256];
    const int b = blockIdx.x, c = blockIdx.y, t = threadIdx.x;
    const int* h = hist2 + ((size_t)c * NBINS + b) * 4096;
    int loc[16], s = 0;
    #pragma unroll
    for (int i = 0; i < 16; ++i) { loc[i] = h[t * 16 + i]; s += loc[i]; }
    part[t] = s;
    __syncthreads();
    if (t == 0) {
        int run = 0;
        for (int i = 0; i < 256; ++i) { int v = part[i]; part[i] = run; run += v; }
    }
    __syncthreads();
    const int lr = rank_target(b) - below[c * NBINS + b];
    int cc = part[t];
    #pragma unroll
    for (int i = 0; i < 16; ++i) {
        if (lr >= cc && lr < cc + loc[i]) {
            unsigned bits = ((unsigned)tgt[c * NBINS + b] << 18) |
                            ((unsigned)(t * 16 + i) << 6) | 63u;
            bounds[c * NBINS + b] = __uint_as_float(bits);
        }
        cc += loc[i];
    }
}

// Pass 4: cumulative register accumulators — no scatter, no LDS-atomic contention.
// cum_b = {count, T, Q} over conf <= bounds[b]; bins recovered by differencing.
__global__ __launch_bounds__(256) void k_accum(const float* __restrict__ probsT,
                                               const float* __restrict__ bounds,
                                               float* __restrict__ accCum,  // [C][15][3]
                                               float* __restrict__ accTot)  // [C][2]
{
    const int c = blockIdx.y, t = threadIdx.x;
    float bnd[NBINS];
    #pragma unroll
    for (int b = 0; b < NBINS; ++b) bnd[b] = bounds[c * NBINS + b];
    float cN[NBINS], cT[NBINS], cQ[NBINS];
    #pragma unroll
    for (int b = 0; b < NBINS; ++b) { cN[b] = 0.f; cT[b] = 0.f; cQ[b] = 0.f; }
    float tT = 0.f, tQ = 0.f;
    const size_t base = (size_t)c * NROWS;
    const int start = blockIdx.x * CHUNK;
    const int end = min(NROWS, start + CHUNK);
    for (int i = start + t; i < end; i += 256) {
        float conf = probsT[base + i];
        float c2 = conf * conf;
        tT += conf; tQ += c2;
        #pragma unroll
        for (int b = 0; b < NBINS; ++b) {
            float m = (conf <= bnd[b]) ? 1.0f : 0.0f;
            cN[b] += m;
            cT[b] = fmaf(m, conf, cT[b]);
            cQ[b] = fmaf(m, c2, cQ[b]);
        }
    }
    #pragma unroll
    for (int b = 0; b < NBINS; ++b) {
        cN[b] = wave_sum(cN[b]); cT[b] = wave_sum(cT[b]); cQ[b] = wave_sum(cQ[b]);
    }
    tT = wave_sum(tT); tQ = wave_sum(tQ);
    if ((t & 63) == 0) {
        #pragma unroll
        for (int b = 0; b < NBINS; ++b) {
            atomicAdd(&accCum[(c * NBINS + b) * 3 + 0], cN[b]);
            atomicAdd(&accCum[(c * NBINS + b) * 3 + 1], cT[b]);
            atomicAdd(&accCum[(c * NBINS + b) * 3 + 2], cQ[b]);
        }
        atomicAdd(&accTot[c * 2 + 0], tT);
        atomicAdd(&accTot[c * 2 + 1], tQ);
    }
}

// Pass 5: label correction — only 500K elements have lab=1 (in their label's class)
__global__ __launch_bounds__(256) void k_label(const float* __restrict__ probsT,
                                               const int* __restrict__ labels,
                                               const float* __restrict__ bounds,
                                               float* __restrict__ accLab)  // [C][15][2]
{
    const int n = blockIdx.x * 256 + threadIdx.x;
    if (n >= NROWS) return;
    const int c = labels[n];
    const float conf = probsT[(size_t)c * NROWS + n];
    const float* bd = bounds + c * NBINS;
    if (conf > bd[0]) {
        int idx = 0;
        #pragma unroll
        for (int b = 1; b < NBINS; ++b) idx += (conf > bd[b]) ? 1 : 0;
        atomicAdd(&accLab[(c * NBINS + idx) * 2 + 0], 1.0f);
        atomicAdd(&accLab[(c * NBINS + idx) * 2 + 1], conf);
    }
}

// Pass 6: closed-form LOO combine in double, single scalar out
__global__ __launch_bounds__(256) void k_final(const float* __restrict__ accCum,
                                               const float* __restrict__ accTot,
                                               const float* __restrict__ accLab,
                                               float* __restrict__ out) {
    __shared__ double red[256];
    const int t = threadIdx.x;
    double local = 0.0;
    for (int k = t; k < NCLS * NBINS; k += 256) {
        int c = k / NBINS, b = k - c * NBINS;
        double n, T, Q;
        if (b < NBINS - 1) {
            n = (double)accCum[(c * NBINS + b + 1) * 3 + 0] - (double)accCum[(c * NBINS + b) * 3 + 0];
            T = (double)accCum[(c * NBINS + b + 1) * 3 + 1] - (double)accCum[(c * NBINS + b) * 3 + 1];
            Q = (double)accCum[(c * NBINS + b + 1) * 3 + 2] - (double)accCum[(c * NBINS + b) * 3 + 2];
        } else {
            n = (double)NROWS - (double)accCum[(c * NBINS + 14) * 3 + 0];
            T = (double)accTot[c * 2 + 0] - (double)accCum[(c * NBINS + 14) * 3 + 1];
            Q = (double)accTot[c * 2 + 1] - (double)accCum[(c * NBINS + 14) * 3 + 2];
        }
        double S = accLab[k * 2 + 0], T1 = accLab[k * 2 + 1];
        if (n > 1.5) {
            double inv = 1.0 / (n - 1.0);
            double a0 = S * inv, a1 = (S - 1.0) * inv;
            local += Q - 2.0 * a0 * T + 2.0 * T1 * inv + (n - S) * a0 * a0 + S * a1 * a1;
        }
    }
    red[t] = local;
    __syncthreads();
    for (int s = 128; s; s >>= 1) {
        if (t < s) red[t] += red[t + s];
        __syncthreads();
    }
    if (t == 0) out[0] = (float)(red[0] / ((double)NROWS * (double)NCLS));
}

extern "C" void kernel_launch(void* const* d_in, const int* in_sizes, int n_in,
                              void* d_out, int out_size, void* d_ws, size_t ws_size,
                              hipStream_t stream) {
    const float* logits = (const float*)d_in[0];
    const int* labels = (const int*)d_in[1];
    float* out = (float*)d_out;
    char* ws = (char*)d_ws;
    size_t off = 0;
    auto alloc = [&](size_t bytes) -> void* {
        off = (off + 255) & ~(size_t)255;
        void* p = ws + off;
        off += bytes;
        return p;
    };
    float* probsT = (float*)alloc((size_t)NCLS * NROWS * 4);         // 200 MB
    int*   hist1  = (int*)alloc((size_t)NCLS * 4096 * 4);            // 1.6 MB
    int*   tgt    = (int*)alloc((size_t)NCLS * NBINS * 4);
    int*   below  = (int*)alloc((size_t)NCLS * NBINS * 4);
    int*   hist2  = (int*)alloc((size_t)NCLS * NBINS * 4096 * 4);    // 24.6 MB
    float* bounds = (float*)alloc((size_t)NCLS * NBINS * 4);
    float* accCum = (float*)alloc((size_t)NCLS * NBINS * 3 * 4);
    float* accTot = (float*)alloc((size_t)NCLS * 2 * 4);
    float* accLab = (float*)alloc((size_t)NCLS * NBINS * 2 * 4);
    if (off > ws_size) {
        // detectable sentinel: NaN in output
        hipMemsetAsync(d_out, 0xFF, 4, stream);
        return;
    }
    hipMemsetAsync(hist1, 0, (size_t)NCLS * 4096 * 4, stream);
    hipMemsetAsync(hist2, 0, (size_t)NCLS * NBINS * 4096 * 4, stream);
    hipMemsetAsync(accCum, 0, (size_t)NCLS * NBINS * 3 * 4, stream);
    hipMemsetAsync(accTot, 0, (size_t)NCLS * 2 * 4, stream);
    hipMemsetAsync(accLab, 0, (size_t)NCLS * NBINS * 2 * 4, stream);

    k_softmax_t<<<(NROWS + 63) / 64, 256, 0, stream>>>(logits, probsT);
    dim3 g32(32, NCLS);
    k_hist1<<<g32, 256, 0, stream>>>(probsT, hist1);
    k_sel1<<<NCLS, 256, 0, stream>>>(hist1, tgt, below);
    k_hist2<<<g32, 256, 0, stream>>>(probsT, tgt, hist2);
    k_sel2<<<dim3(NBINS, NCLS), 256, 0, stream>>>(hist2, tgt, below, bounds);
    k_accum<<<g32, 256, 0, stream>>>(probsT, bounds, accCum, accTot);
    k_label<<<(NROWS + 255) / 256, 256, 0, stream>>>(probsT, labels, bounds, accLab);
    k_final<<<1, 256, 0, stream>>>(accCum, accTot, accLab, out);
}

// Round 2
// 808.612 us; speedup vs baseline: 1.2941x; 1.2941x over previous
//
#include <hip/hip_runtime.h>
#include <stdint.h>

#define NROWS 500000
#define NROWS4 125000
#define NCLS 100
#define NBINS 15
#define NSUB 1024
#define CH4 3907   // ceil(125000/32) float4s per block

__device__ __forceinline__ int rank_target(int b) {
    if (b == 0) return 0;
    const float step = 500000.0f / 15.0f;   // float32-rounded, mimics jnp.linspace
    return (int)floorf((float)b * step);
}

__device__ __forceinline__ float wave_sum(float v) {
    #pragma unroll
    for (int o = 32; o; o >>= 1) v += __shfl_xor(v, o, 64);
    return v;
}

// Pass 1: row softmax of logits [N][C], write transposed probsT [C][N]
__global__ __launch_bounds__(256) void k_softmax_t(const float* __restrict__ logits,
                                                   float* __restrict__ probsT) {
    __shared__ float tile[64][101];   // stride 101: store-phase column reads hit all 32 banks
    __shared__ float red[256];
    __shared__ float mx[64];
    __shared__ float inv[64];
    const int row0 = blockIdx.x * 64;
    const int rows = min(64, NROWS - row0);
    const int t = threadIdx.x;
    const int total = rows * NCLS;
    for (int k = t; k < total; k += 256) {
        int r = k / NCLS, c = k - r * NCLS;
        tile[r][c] = logits[(size_t)(row0 + r) * NCLS + c];
    }
    __syncthreads();
    const int r = t >> 2, q = t & 3;   // 4 threads per row
    if (r < rows) {
        float m = -1e30f;
        #pragma unroll
        for (int c = 0; c < 25; ++c) m = fmaxf(m, tile[r][q * 25 + c]);
        red[t] = m;
    }
    __syncthreads();
    if (r < rows && q == 0)
        mx[r] = fmaxf(fmaxf(red[t], red[t + 1]), fmaxf(red[t + 2], red[t + 3]));
    __syncthreads();
    if (r < rows) {
        float m = mx[r], s = 0.f;
        #pragma unroll
        for (int c = 0; c < 25; ++c) {
            float e = __expf(tile[r][q * 25 + c] - m);
            tile[r][q * 25 + c] = e;
            s += e;
        }
        red[t] = s;
    }
    __syncthreads();
    if (r < rows && q == 0)
        inv[r] = 1.0f / (red[t] + red[t + 1] + red[t + 2] + red[t + 3]);
    __syncthreads();
    // store: float4 of 4 consecutive rows per class; rows is 64 or 32 -> shift 4 or 3
    const int shift = (rows == 64) ? 4 : 3;
    const int gq = 1 << shift;
    const int ng = NCLS << shift;
    for (int k = t; k < ng; k += 256) {
        int c = k >> shift, g = k & (gq - 1);
        int rr = g << 2;
        float4 o;
        o.x = tile[rr + 0][c] * inv[rr + 0];
        o.y = tile[rr + 1][c] * inv[rr + 1];
        o.z = tile[rr + 2][c] * inv[rr + 2];
        o.w = tile[rr + 3][c] * inv[rr + 3];
        *(float4*)(probsT + (size_t)c * NROWS + row0 + rr) = o;
    }
}

// Pass 2: per-class L1 histogram, 4 bank-rotated LDS copies to cut same-address
// atomic serialization 4x (copy k stores bucket B at (B+8k)&4095 -> 4 distinct banks)
__global__ __launch_bounds__(256) void k_hist1(const float4* __restrict__ probsT4,
                                               int* __restrict__ hist1) {
    __shared__ int h[4][4096];   // 64 KB
    const int c = blockIdx.y, t = threadIdx.x;
    int4* hz = (int4*)&h[0][0];
    for (int i = t; i < 4096; i += 256) hz[i] = make_int4(0, 0, 0, 0);
    __syncthreads();
    const int copy = t & 3;
    const int rot = copy * 8;
    const size_t base = (size_t)c * NROWS4;
    const int start = blockIdx.x * CH4;
    const int end = min(NROWS4, start + CH4);
    for (int i = start + t; i < end; i += 256) {
        float4 v = probsT4[base + i];
        atomicAdd(&h[copy][((__float_as_uint(v.x) >> 18) + rot) & 4095], 1);
        atomicAdd(&h[copy][((__float_as_uint(v.y) >> 18) + rot) & 4095], 1);
        atomicAdd(&h[copy][((__float_as_uint(v.z) >> 18) + rot) & 4095], 1);
        atomicAdd(&h[copy][((__float_as_uint(v.w) >> 18) + rot) & 4095], 1);
    }
    __syncthreads();
    for (int i = t; i < 4096; i += 256) {
        int s = h[0][i] + h[1][(i + 8) & 4095] + h[2][(i + 16) & 4095] + h[3][(i + 24) & 4095];
        if (s) atomicAdd(&hist1[c * 4096 + i], s);
    }
}

// Select L1 bucket per rank target; also dedupe duplicate targets via owner[]
__global__ __launch_bounds__(256) void k_sel1(const int* __restrict__ hist1,
                                              int* __restrict__ tgt,
                                              int* __restrict__ below,
                                              int* __restrict__ owner) {
    __shared__ int part[256];
    __shared__ int stgt[NBINS];
    const int c = blockIdx.x, t = threadIdx.x;
    int loc[16], s = 0;
    #pragma unroll
    for (int i = 0; i < 16; ++i) { loc[i] = hist1[c * 4096 + t * 16 + i]; s += loc[i]; }
    part[t] = s;
    __syncthreads();
    if (t == 0) {
        int run = 0;
        for (int i = 0; i < 256; ++i) { int v = part[i]; part[i] = run; run += v; }
    }
    __syncthreads();
    const int cum0 = part[t];
    for (int b = 0; b < NBINS; ++b) {
        const int f = rank_target(b);
        int cc = cum0;
        #pragma unroll
        for (int i = 0; i < 16; ++i) {
            if (f >= cc && f < cc + loc[i]) {
                stgt[b] = t * 16 + i;
                below[c * NBINS + b] = cc;
            }
            cc += loc[i];
        }
    }
    __syncthreads();
    if (t == 0) {
        int ow = 0;
        for (int b = 0; b < NBINS; ++b) {
            if (b && stgt[b] != stgt[b - 1]) {} else if (b) { owner[c * NBINS + b] = ow; tgt[c * NBINS + b] = stgt[b]; continue; }
            ow = b;
            owner[c * NBINS + b] = ow;
            tgt[c * NBINS + b] = stgt[b];
        }
    }
}

// Pass 3: refine — branchless LDS binary search for target-bucket membership,
// 1024 sub-buckets (bits 8..17); only first-occurrence (owner) slot is filled
__global__ __launch_bounds__(256) void k_hist2(const float4* __restrict__ probsT4,
                                               const int* __restrict__ tgt,
                                               int* __restrict__ hist2) {
    __shared__ int stg[16];
    const int c = blockIdx.y, t = threadIdx.x;
    if (t < 16) stg[t] = (t < NBINS) ? tgt[c * NBINS + t] : 0x7FFFFFFF;
    __syncthreads();
    int* h2 = hist2 + (size_t)c * NBINS * NSUB;
    const size_t base = (size_t)c * NROWS4;
    const int start = blockIdx.x * CH4;
    const int end = min(NROWS4, start + CH4);
    for (int i = start + t; i < end; i += 256) {
        float4 v = probsT4[base + i];
        unsigned bx[4] = {__float_as_uint(v.x), __float_as_uint(v.y),
                          __float_as_uint(v.z), __float_as_uint(v.w)};
        #pragma unroll
        for (int e = 0; e < 4; ++e) {
            int k1 = (int)(bx[e] >> 18);
            int idx = 0;                      // lower_bound: idx = #{tg < k1}
            idx += (stg[idx + 7] < k1) ? 8 : 0;
            idx += (stg[idx + 3] < k1) ? 4 : 0;
            idx += (stg[idx + 1] < k1) ? 2 : 0;
            idx += (stg[idx] < k1) ? 1 : 0;
            if (idx < NBINS && stg[idx] == k1)
                atomicAdd(&h2[idx * NSUB + ((bx[e] >> 8) & 0x3FF)], 1);
        }
    }
}

// Select sub-bucket; boundary = top float of 256-ULP sub-bucket; also emit the
// exact rank cnt = #{conf <= bound} so the accum pass needs no counting at all
__global__ __launch_bounds__(256) void k_sel2(const int* __restrict__ hist2,
                                              const int* __restrict__ tgt,
                                              const int* __restrict__ below,
                                              const int* __restrict__ owner,
                                              float* __restrict__ bounds,
                                              int* __restrict__ cnt) {
    __shared__ int part[256];
    const int b = blockIdx.x, c = blockIdx.y, t = threadIdx.x;
    const int* h = hist2 + ((size_t)c * NBINS + owner[c * NBINS + b]) * NSUB;
    int loc[4], s = 0;
    #pragma unroll
    for (int i = 0; i < 4; ++i) { loc[i] = h[t * 4 + i]; s += loc[i]; }
    part[t] = s;
    __syncthreads();
    if (t == 0) {
        int run = 0;
        for (int i = 0; i < 256; ++i) { int v = part[i]; part[i] = run; run += v; }
    }
    __syncthreads();
    const int lr = rank_target(b) - below[c * NBINS + b];
    int cc = part[t];
    #pragma unroll
    for (int i = 0; i < 4; ++i) {
        if (lr >= cc && lr < cc + loc[i]) {
            unsigned bits = ((unsigned)tgt[c * NBINS + b] << 18) |
                            ((unsigned)(t * 4 + i) << 8) | 0xFFu;
            bounds[c * NBINS + b] = __uint_as_float(bits);
            cnt[c * NBINS + b] = below[c * NBINS + b] + cc + loc[i];
        }
        cc += loc[i];
    }
}

// Pass 4: min-trick accumulation. cumT[b] = sum min(conf,bnd[b]) - bnd[b]*above_b
// (above from exact cnt), so per bin per element: min + add + fma only.
// accA layout per class: [0..14]=sum min, [15..29]=sum min^2, [30]=sumT, [31]=sumQ
__global__ __launch_bounds__(256) void k_accum(const float4* __restrict__ probsT4,
                                               const float* __restrict__ bounds,
                                               float* __restrict__ accA) {
    __shared__ float lred[4][32];
    const int c = blockIdx.y, t = threadIdx.x;
    float bnd[NBINS];
    #pragma unroll
    for (int b = 0; b < NBINS; ++b) bnd[b] = bounds[c * NBINS + b];
    float mt[NBINS], mq[NBINS];
    #pragma unroll
    for (int b = 0; b < NBINS; ++b) { mt[b] = 0.f; mq[b] = 0.f; }
    float tT = 0.f, tQ = 0.f;
    const size_t base = (size_t)c * NROWS4;
    const int start = blockIdx.x * CH4;
    const int end = min(NROWS4, start + CH4);
    for (int i = start + t; i < end; i += 256) {
        float4 v = probsT4[base + i];
        tT += (v.x + v.y) + (v.z + v.w);
        tQ = fmaf(v.x, v.x, fmaf(v.y, v.y, fmaf(v.z, v.z, fmaf(v.w, v.w, tQ))));
        #pragma unroll
        for (int b = 0; b < NBINS; ++b) {
            float m0 = fminf(v.x, bnd[b]), m1 = fminf(v.y, bnd[b]);
            float m2 = fminf(v.z, bnd[b]), m3 = fminf(v.w, bnd[b]);
            mt[b] += (m0 + m1) + (m2 + m3);
            mq[b] = fmaf(m0, m0, fmaf(m1, m1, fmaf(m2, m2, fmaf(m3, m3, mq[b]))));
        }
    }
    const int w = t >> 6, lane = t & 63;
    float vals[32];
    #pragma unroll
    for (int b = 0; b < NBINS; ++b) { vals[b] = mt[b]; vals[NBINS + b] = mq[b]; }
    vals[30] = tT; vals[31] = tQ;
    #pragma unroll
    for (int j = 0; j < 32; ++j) vals[j] = wave_sum(vals[j]);
    if (lane == 0) {
        #pragma unroll
        for (int j = 0; j < 32; ++j) lred[w][j] = vals[j];
    }
    __syncthreads();
    if (t < 32) {
        float s = lred[0][t] + lred[1][t] + lred[2][t] + lred[3][t];
        atomicAdd(&accA[c * 32 + t], s);
    }
}

// Pass 5: label correction — only elements with lab=1 (their label's class)
__global__ __launch_bounds__(256) void k_label(const float* __restrict__ probsT,
                                               const int* __restrict__ labels,
                                               const float* __restrict__ bounds,
                                               float* __restrict__ accLab) {
    const int n = blockIdx.x * 256 + threadIdx.x;
    if (n >= NROWS) return;
    const int c = labels[n];
    const float conf = probsT[(size_t)c * NROWS + n];
    const float* bd = bounds + c * NBINS;
    if (conf > bd[0]) {
        int idx = 0;
        #pragma unroll
        for (int b = 1; b < NBINS; ++b) idx += (conf > bd[b]) ? 1 : 0;
        atomicAdd(&accLab[(c * NBINS + idx) * 2 + 0], 1.0f);
        atomicAdd(&accLab[(c * NBINS + idx) * 2 + 1], conf);
    }
}

// Pass 6: closed-form LOO combine in double
__global__ __launch_bounds__(256) void k_final(const float* __restrict__ accA,
                                               const int* __restrict__ cnt,
                                               const float* __restrict__ bounds,
                                               const float* __restrict__ accLab,
                                               float* __restrict__ out) {
    __shared__ double red[256];
    const int t = threadIdx.x;
    double local = 0.0;
    for (int k = t; k < NCLS * NBINS; k += 256) {
        int c = k / NBINS, b = k - c * NBINS;
        double n, T, Q;
        double m_b = accA[c * 32 + b];
        double q_b = accA[c * 32 + NBINS + b];
        double bd_b = bounds[c * NBINS + b];
        double ab_b = (double)(NROWS - cnt[c * NBINS + b]);
        double cT_b = m_b - bd_b * ab_b;
        double cQ_b = q_b - bd_b * bd_b * ab_b;
        if (b < NBINS - 1) {
            double m_u = accA[c * 32 + b + 1];
            double q_u = accA[c * 32 + NBINS + b + 1];
            double bd_u = bounds[c * NBINS + b + 1];
            double ab_u = (double)(NROWS - cnt[c * NBINS + b + 1]);
            n = (double)(cnt[c * NBINS + b + 1] - cnt[c * NBINS + b]);
            T = (m_u - bd_u * ab_u) - cT_b;
            Q = (q_u - bd_u * bd_u * ab_u) - cQ_b;
        } else {
            n = (double)(NROWS - cnt[c * NBINS + 14]);
            T = (double)accA[c * 32 + 30] - cT_b;
            Q = (double)accA[c * 32 + 31] - cQ_b;
        }
        double S = accLab[k * 2 + 0], T1 = accLab[k * 2 + 1];
        if (n > 1.5) {
            double inv = 1.0 / (n - 1.0);
            double a0 = S * inv, a1 = (S - 1.0) * inv;
            local += Q - 2.0 * a0 * T + 2.0 * T1 * inv + (n - S) * a0 * a0 + S * a1 * a1;
        }
    }
    red[t] = local;
    __syncthreads();
    for (int s = 128; s; s >>= 1) {
        if (t < s) red[t] += red[t + s];
        __syncthreads();
    }
    if (t == 0) out[0] = (float)(red[0] / ((double)NROWS * (double)NCLS));
}

extern "C" void kernel_launch(void* const* d_in, const int* in_sizes, int n_in,
                              void* d_out, int out_size, void* d_ws, size_t ws_size,
                              hipStream_t stream) {
    const float* logits = (const float*)d_in[0];
    const int* labels = (const int*)d_in[1];
    float* out = (float*)d_out;
    char* ws = (char*)d_ws;
    size_t off = 0;
    auto alloc = [&](size_t bytes) -> void* {
        off = (off + 255) & ~(size_t)255;
        void* p = ws + off;
        off += bytes;
        return p;
    };
    float* probsT = (float*)alloc((size_t)NCLS * NROWS * 4);              // 200 MB
    // --- zeroed region (contiguous, single memset) ---
    char* zbase = ws + ((off + 255) & ~(size_t)255);
    int*   hist1  = (int*)alloc((size_t)NCLS * 4096 * 4);                 // 1.6 MB
    int*   hist2  = (int*)alloc((size_t)NCLS * NBINS * NSUB * 4);         // 6.1 MB
    float* accA   = (float*)alloc((size_t)NCLS * 32 * 4);
    float* accLab = (float*)alloc((size_t)NCLS * NBINS * 2 * 4);
    size_t zlen = (size_t)((ws + off) - zbase);
    // --- written-before-read region ---
    int*   tgt    = (int*)alloc((size_t)NCLS * NBINS * 4);
    int*   below  = (int*)alloc((size_t)NCLS * NBINS * 4);
    int*   owner  = (int*)alloc((size_t)NCLS * NBINS * 4);
    float* bounds = (float*)alloc((size_t)NCLS * NBINS * 4);
    int*   cnt    = (int*)alloc((size_t)NCLS * NBINS * 4);
    if (off > ws_size) {
        hipMemsetAsync(d_out, 0xFF, 4, stream);   // NaN sentinel
        return;
    }
    hipMemsetAsync(zbase, 0, zlen, stream);

    k_softmax_t<<<(NROWS + 63) / 64, 256, 0, stream>>>(logits, probsT);
    dim3 g32(32, NCLS);
    k_hist1<<<g32, 256, 0, stream>>>((const float4*)probsT, hist1);
    k_sel1<<<NCLS, 256, 0, stream>>>(hist1, tgt, below, owner);
    k_hist2<<<g32, 256, 0, stream>>>((const float4*)probsT, tgt, hist2);
    k_sel2<<<dim3(NBINS, NCLS), 256, 0, stream>>>(hist2, tgt, below, owner, bounds, cnt);
    k_accum<<<g32, 256, 0, stream>>>((const float4*)probsT, bounds, accA);
    k_label<<<(NROWS + 255) / 256, 256, 0, stream>>>(probsT, labels, bounds, accLab);
    k_final<<<1, 256, 0, stream>>>(accA, cnt, bounds, accLab, out);
}

// Round 3
// 704.652 us; speedup vs baseline: 1.4850x; 1.1475x over previous
//
#include <hip/hip_runtime.h>
#include <stdint.h>

#define NROWS 500000
#define NROWS4 125000
#define NCLS 100
#define NBINS 15
#define NSUB 512
#define B1 8
#define CH1 15625   // ceil(125000/8) float4s per hist1 block
#define B2 4
#define CH2 31250   // 125000/4 float4s per hist2 block
#define CH4 3907    // ceil(125000/32) float4s per accum block

__device__ __forceinline__ int rank_target(int b) {
    if (b == 0) return 0;
    const float step = 500000.0f / 15.0f;   // float32-rounded, mimics jnp.linspace
    return (int)floorf((float)b * step);
}

__device__ __forceinline__ float wave_sum(float v) {
    #pragma unroll
    for (int o = 32; o; o >>= 1) v += __shfl_xor(v, o, 64);
    return v;
}

// Pass 1: row softmax of logits [N][C], write transposed probsT [C][N]
__global__ __launch_bounds__(256) void k_softmax_t(const float* __restrict__ logits,
                                                   float* __restrict__ probsT) {
    __shared__ float tile[64][101];
    __shared__ float red[256];
    __shared__ float mx[64];
    __shared__ float inv[64];
    const int row0 = blockIdx.x * 64;
    const int rows = min(64, NROWS - row0);
    const int t = threadIdx.x;
    const int total = rows * NCLS;
    for (int k = t; k < total; k += 256) {
        int r = k / NCLS, c = k - r * NCLS;
        tile[r][c] = logits[(size_t)(row0 + r) * NCLS + c];
    }
    __syncthreads();
    const int r = t >> 2, q = t & 3;   // 4 threads per row
    if (r < rows) {
        float m = -1e30f;
        #pragma unroll
        for (int c = 0; c < 25; ++c) m = fmaxf(m, tile[r][q * 25 + c]);
        red[t] = m;
    }
    __syncthreads();
    if (r < rows && q == 0)
        mx[r] = fmaxf(fmaxf(red[t], red[t + 1]), fmaxf(red[t + 2], red[t + 3]));
    __syncthreads();
    if (r < rows) {
        float m = mx[r], s = 0.f;
        #pragma unroll
        for (int c = 0; c < 25; ++c) {
            float e = __expf(tile[r][q * 25 + c] - m);
            tile[r][q * 25 + c] = e;
            s += e;
        }
        red[t] = s;
    }
    __syncthreads();
    if (r < rows && q == 0)
        inv[r] = 1.0f / (red[t] + red[t + 1] + red[t + 2] + red[t + 3]);
    __syncthreads();
    const int shift = (rows == 64) ? 4 : 3;
    const int gq = 1 << shift;
    const int ng = NCLS << shift;
    for (int k = t; k < ng; k += 256) {
        int c = k >> shift, g = k & (gq - 1);
        int rr = g << 2;
        float4 o;
        o.x = tile[rr + 0][c] * inv[rr + 0];
        o.y = tile[rr + 1][c] * inv[rr + 1];
        o.z = tile[rr + 2][c] * inv[rr + 2];
        o.w = tile[rr + 3][c] * inv[rr + 3];
        *(float4*)(probsT + (size_t)c * NROWS + row0 + rr) = o;
    }
}

// Pass 2: per-class L1 histogram, 2 bank-rotated LDS copies; NON-ATOMIC flush
// to a private copy per blockIdx.x -> zero global atomics.
__global__ __launch_bounds__(256) void k_hist1(const float4* __restrict__ probsT4,
                                               int* __restrict__ hist1p) {
    __shared__ int h[2][4096];   // 32 KB
    const int c = blockIdx.y, t = threadIdx.x;
    int4* hz = (int4*)&h[0][0];
    for (int i = t; i < 2048; i += 256) hz[i] = make_int4(0, 0, 0, 0);
    __syncthreads();
    const int copy = t & 1;
    const int rot = copy << 4;
    const size_t base = (size_t)c * NROWS4;
    const int start = blockIdx.x * CH1;
    const int end = min(NROWS4, start + CH1);
    for (int i = start + t; i < end; i += 256) {
        float4 v = probsT4[base + i];
        atomicAdd(&h[copy][((__float_as_uint(v.x) >> 18) + rot) & 4095], 1);
        atomicAdd(&h[copy][((__float_as_uint(v.y) >> 18) + rot) & 4095], 1);
        atomicAdd(&h[copy][((__float_as_uint(v.z) >> 18) + rot) & 4095], 1);
        atomicAdd(&h[copy][((__float_as_uint(v.w) >> 18) + rot) & 4095], 1);
    }
    __syncthreads();
    int* out = hist1p + ((size_t)blockIdx.x * NCLS + c) * 4096;
    for (int i = t; i < 4096; i += 256)
        out[i] = h[0][i] + h[1][(i + 16) & 4095];
}

// Select L1 bucket per rank target (sums B1 private copies); dedupe via owner[]
__global__ __launch_bounds__(256) void k_sel1(const int* __restrict__ hist1p,
                                              int* __restrict__ tgt,
                                              int* __restrict__ below,
                                              int* __restrict__ owner) {
    __shared__ int part[256];
    __shared__ int stgt[NBINS];
    const int c = blockIdx.x, t = threadIdx.x;
    int4 acc[4] = {make_int4(0,0,0,0), make_int4(0,0,0,0),
                   make_int4(0,0,0,0), make_int4(0,0,0,0)};
    for (int k = 0; k < B1; ++k) {
        const int4* p = (const int4*)(hist1p + ((size_t)k * NCLS + c) * 4096) + t * 4;
        #pragma unroll
        for (int j = 0; j < 4; ++j) {
            int4 v = p[j];
            acc[j].x += v.x; acc[j].y += v.y; acc[j].z += v.z; acc[j].w += v.w;
        }
    }
    int loc[16];
    #pragma unroll
    for (int j = 0; j < 4; ++j) {
        loc[j * 4 + 0] = acc[j].x; loc[j * 4 + 1] = acc[j].y;
        loc[j * 4 + 2] = acc[j].z; loc[j * 4 + 3] = acc[j].w;
    }
    int s = 0;
    #pragma unroll
    for (int i = 0; i < 16; ++i) s += loc[i];
    part[t] = s;
    __syncthreads();
    if (t == 0) {
        int run = 0;
        for (int i = 0; i < 256; ++i) { int v = part[i]; part[i] = run; run += v; }
    }
    __syncthreads();
    const int cum0 = part[t];
    for (int b = 0; b < NBINS; ++b) {
        const int f = rank_target(b);
        int cc = cum0;
        #pragma unroll
        for (int i = 0; i < 16; ++i) {
            if (f >= cc && f < cc + loc[i]) {
                stgt[b] = t * 16 + i;
                below[c * NBINS + b] = cc;
            }
            cc += loc[i];
        }
    }
    __syncthreads();
    if (t == 0) {
        int ow = 0;
        for (int b = 0; b < NBINS; ++b) {
            if (b == 0 || stgt[b] != stgt[b - 1]) ow = b;
            owner[c * NBINS + b] = ow;
            tgt[c * NBINS + b] = stgt[b];
        }
    }
}

// Pass 3: refine — full 15x512 LDS histogram per block, branchless binary search
// membership, NON-ATOMIC flush to private copy per blockIdx.x.
__global__ __launch_bounds__(256) void k_hist2(const float4* __restrict__ probsT4,
                                               const int* __restrict__ tgt,
                                               int* __restrict__ hist2p) {
    __shared__ int h[NBINS * NSUB];   // 30 KB
    __shared__ int stg[16];
    const int c = blockIdx.y, t = threadIdx.x;
    if (t < 16) stg[t] = (t < NBINS) ? tgt[c * NBINS + t] : 0x7FFFFFFF;
    int4* hz = (int4*)h;
    for (int i = t; i < NBINS * NSUB / 4; i += 256) hz[i] = make_int4(0, 0, 0, 0);
    __syncthreads();
    const size_t base = (size_t)c * NROWS4;
    const int start = blockIdx.x * CH2;
    const int end = min(NROWS4, start + CH2);
    for (int i = start + t; i < end; i += 256) {
        float4 v = probsT4[base + i];
        unsigned bx[4] = {__float_as_uint(v.x), __float_as_uint(v.y),
                          __float_as_uint(v.z), __float_as_uint(v.w)};
        #pragma unroll
        for (int e = 0; e < 4; ++e) {
            int k1 = (int)(bx[e] >> 18);
            int idx = 0;                      // lower_bound: idx = #{tg < k1}
            idx += (stg[idx + 7] < k1) ? 8 : 0;
            idx += (stg[idx + 3] < k1) ? 4 : 0;
            idx += (stg[idx + 1] < k1) ? 2 : 0;
            idx += (stg[idx] < k1) ? 1 : 0;
            if (idx < NBINS && stg[idx] == k1)
                atomicAdd(&h[idx * NSUB + ((bx[e] >> 9) & 0x1FF)], 1);
        }
    }
    __syncthreads();
    int* out = hist2p + ((size_t)blockIdx.x * NCLS + c) * (NBINS * NSUB);
    for (int i = t; i < NBINS * NSUB; i += 256) out[i] = h[i];
}

// Select sub-bucket (sums B2 copies); boundary = top float of 512-ULP sub-bucket;
// emit exact cnt = #{conf <= bound}
__global__ __launch_bounds__(256) void k_sel2(const int* __restrict__ hist2p,
                                              const int* __restrict__ tgt,
                                              const int* __restrict__ below,
                                              const int* __restrict__ owner,
                                              float* __restrict__ bounds,
                                              int* __restrict__ cnt) {
    __shared__ int part[256];
    const int b = blockIdx.x, c = blockIdx.y, t = threadIdx.x;
    const int ow = owner[c * NBINS + b];
    int ax = 0, ay = 0;
    for (int k = 0; k < B2; ++k) {
        int2 v = *(const int2*)(hist2p + ((size_t)k * NCLS + c) * (NBINS * NSUB)
                                + ow * NSUB + t * 2);
        ax += v.x; ay += v.y;
    }
    part[t] = ax + ay;
    __syncthreads();
    if (t == 0) {
        int run = 0;
        for (int i = 0; i < 256; ++i) { int v = part[i]; part[i] = run; run += v; }
    }
    __syncthreads();
    const int lr = rank_target(b) - below[c * NBINS + b];
    int cc = part[t];
    int loc[2] = {ax, ay};
    #pragma unroll
    for (int i = 0; i < 2; ++i) {
        if (lr >= cc && lr < cc + loc[i]) {
            unsigned bits = ((unsigned)tgt[c * NBINS + b] << 18) |
                            ((unsigned)(t * 2 + i) << 9) | 0x1FFu;
            bounds[c * NBINS + b] = __uint_as_float(bits);
            cnt[c * NBINS + b] = below[c * NBINS + b] + cc + loc[i];
        }
        cc += loc[i];
    }
}

// Pass 4: min-trick accumulation (no counting needed — cnt is exact from sel2)
__global__ __launch_bounds__(256) void k_accum(const float4* __restrict__ probsT4,
                                               const float* __restrict__ bounds,
                                               float* __restrict__ accA) {
    __shared__ float lred[4][32];
    const int c = blockIdx.y, t = threadIdx.x;
    float bnd[NBINS];
    #pragma unroll
    for (int b = 0; b < NBINS; ++b) bnd[b] = bounds[c * NBINS + b];
    float mt[NBINS], mq[NBINS];
    #pragma unroll
    for (int b = 0; b < NBINS; ++b) { mt[b] = 0.f; mq[b] = 0.f; }
    float tT = 0.f, tQ = 0.f;
    const size_t base = (size_t)c * NROWS4;
    const int start = blockIdx.x * CH4;
    const int end = min(NROWS4, start + CH4);
    for (int i = start + t; i < end; i += 256) {
        float4 v = probsT4[base + i];
        tT += (v.x + v.y) + (v.z + v.w);
        tQ = fmaf(v.x, v.x, fmaf(v.y, v.y, fmaf(v.z, v.z, fmaf(v.w, v.w, tQ))));
        #pragma unroll
        for (int b = 0; b < NBINS; ++b) {
            float m0 = fminf(v.x, bnd[b]), m1 = fminf(v.y, bnd[b]);
            float m2 = fminf(v.z, bnd[b]), m3 = fminf(v.w, bnd[b]);
            mt[b] += (m0 + m1) + (m2 + m3);
            mq[b] = fmaf(m0, m0, fmaf(m1, m1, fmaf(m2, m2, fmaf(m3, m3, mq[b]))));
        }
    }
    const int w = t >> 6, lane = t & 63;
    float vals[32];
    #pragma unroll
    for (int b = 0; b < NBINS; ++b) { vals[b] = mt[b]; vals[NBINS + b] = mq[b]; }
    vals[30] = tT; vals[31] = tQ;
    #pragma unroll
    for (int j = 0; j < 32; ++j) vals[j] = wave_sum(vals[j]);
    if (lane == 0) {
        #pragma unroll
        for (int j = 0; j < 32; ++j) lred[w][j] = vals[j];
    }
    __syncthreads();
    if (t < 32) {
        float s = lred[0][t] + lred[1][t] + lred[2][t] + lred[3][t];
        atomicAdd(&accA[c * 32 + t], s);
    }
}

// Pass 5: label correction
__global__ __launch_bounds__(256) void k_label(const float* __restrict__ probsT,
                                               const int* __restrict__ labels,
                                               const float* __restrict__ bounds,
                                               float* __restrict__ accLab) {
    const int n = blockIdx.x * 256 + threadIdx.x;
    if (n >= NROWS) return;
    const int c = labels[n];
    const float conf = probsT[(size_t)c * NROWS + n];
    const float* bd = bounds + c * NBINS;
    if (conf > bd[0]) {
        int idx = 0;
        #pragma unroll
        for (int b = 1; b < NBINS; ++b) idx += (conf > bd[b]) ? 1 : 0;
        atomicAdd(&accLab[(c * NBINS + idx) * 2 + 0], 1.0f);
        atomicAdd(&accLab[(c * NBINS + idx) * 2 + 1], conf);
    }
}

// Pass 6: closed-form LOO combine in double
__global__ __launch_bounds__(256) void k_final(const float* __restrict__ accA,
                                               const int* __restrict__ cnt,
                                               const float* __restrict__ bounds,
                                               const float* __restrict__ accLab,
                                               float* __restrict__ out) {
    __shared__ double red[256];
    const int t = threadIdx.x;
    double local = 0.0;
    for (int k = t; k < NCLS * NBINS; k += 256) {
        int c = k / NBINS, b = k - c * NBINS;
        double n, T, Q;
        double m_b = accA[c * 32 + b];
        double q_b = accA[c * 32 + NBINS + b];
        double bd_b = bounds[c * NBINS + b];
        double ab_b = (double)(NROWS - cnt[c * NBINS + b]);
        double cT_b = m_b - bd_b * ab_b;
        double cQ_b = q_b - bd_b * bd_b * ab_b;
        if (b < NBINS - 1) {
            double m_u = accA[c * 32 + b + 1];
            double q_u = accA[c * 32 + NBINS + b + 1];
            double bd_u = bounds[c * NBINS + b + 1];
            double ab_u = (double)(NROWS - cnt[c * NBINS + b + 1]);
            n = (double)(cnt[c * NBINS + b + 1] - cnt[c * NBINS + b]);
            T = (m_u - bd_u * ab_u) - cT_b;
            Q = (q_u - bd_u * bd_u * ab_u) - cQ_b;
        } else {
            n = (double)(NROWS - cnt[c * NBINS + 14]);
            T = (double)accA[c * 32 + 30] - cT_b;
            Q = (double)accA[c * 32 + 31] - cQ_b;
        }
        double S = accLab[k * 2 + 0], T1 = accLab[k * 2 + 1];
        if (n > 1.5) {
            double inv = 1.0 / (n - 1.0);
            double a0 = S * inv, a1 = (S - 1.0) * inv;
            local += Q - 2.0 * a0 * T + 2.0 * T1 * inv + (n - S) * a0 * a0 + S * a1 * a1;
        }
    }
    red[t] = local;
    __syncthreads();
    for (int s = 128; s; s >>= 1) {
        if (t < s) red[t] += red[t + s];
        __syncthreads();
    }
    if (t == 0) out[0] = (float)(red[0] / ((double)NROWS * (double)NCLS));
}

extern "C" void kernel_launch(void* const* d_in, const int* in_sizes, int n_in,
                              void* d_out, int out_size, void* d_ws, size_t ws_size,
                              hipStream_t stream) {
    const float* logits = (const float*)d_in[0];
    const int* labels = (const int*)d_in[1];
    float* out = (float*)d_out;
    char* ws = (char*)d_ws;
    size_t off = 0;
    auto alloc = [&](size_t bytes) -> void* {
        off = (off + 255) & ~(size_t)255;
        void* p = ws + off;
        off += bytes;
        return p;
    };
    float* probsT = (float*)alloc((size_t)NCLS * NROWS * 4);               // 200 MB
    int*   hist1p = (int*)alloc((size_t)B1 * NCLS * 4096 * 4);             // 13.1 MB
    int*   hist2p = (int*)alloc((size_t)B2 * NCLS * NBINS * NSUB * 4);     // 12.3 MB
    // --- zeroed region (contiguous, single small memset) ---
    char* zbase = ws + ((off + 255) & ~(size_t)255);
    float* accA   = (float*)alloc((size_t)NCLS * 32 * 4);
    float* accLab = (float*)alloc((size_t)NCLS * NBINS * 2 * 4);
    size_t zlen = (size_t)((ws + off) - zbase);
    // --- written-before-read region ---
    int*   tgt    = (int*)alloc((size_t)NCLS * NBINS * 4);
    int*   below  = (int*)alloc((size_t)NCLS * NBINS * 4);
    int*   owner  = (int*)alloc((size_t)NCLS * NBINS * 4);
    float* bounds = (float*)alloc((size_t)NCLS * NBINS * 4);
    int*   cnt    = (int*)alloc((size_t)NCLS * NBINS * 4);
    if (off > ws_size) {
        hipMemsetAsync(d_out, 0xFF, 4, stream);   // NaN sentinel
        return;
    }
    hipMemsetAsync(zbase, 0, zlen, stream);

    k_softmax_t<<<(NROWS + 63) / 64, 256, 0, stream>>>(logits, probsT);
    k_hist1<<<dim3(B1, NCLS), 256, 0, stream>>>((const float4*)probsT, hist1p);
    k_sel1<<<NCLS, 256, 0, stream>>>(hist1p, tgt, below, owner);
    k_hist2<<<dim3(B2, NCLS), 256, 0, stream>>>((const float4*)probsT, tgt, hist2p);
    k_sel2<<<dim3(NBINS, NCLS), 256, 0, stream>>>(hist2p, tgt, below, owner, bounds, cnt);
    k_accum<<<dim3(32, NCLS), 256, 0, stream>>>((const float4*)probsT, bounds, accA);
    k_label<<<(NROWS + 255) / 256, 256, 0, stream>>>(probsT, labels, bounds, accLab);
    k_final<<<1, 256, 0, stream>>>(accA, cnt, bounds, accLab, out);
}

// Round 4
// 639.929 us; speedup vs baseline: 1.6352x; 1.1011x over previous
//
#include <hip/hip_runtime.h>
#include <stdint.h>

#define NROWS 500000
#define NROWS4 125000
#define NCLS 100
#define NBINS 15
#define NSUB 64          // sub-bucket = 4096 ULP; ~70 elems/sub near mode -> rank err << tolerance
#define B1 14
#define CH1 8929         // ceil(125000/14) float4s per hist1 block
#define B2 16
#define CH2 7813         // ceil(125000/16) float4s per scan2 block
#define HSZ (NBINS * NSUB)   // 960

__device__ __forceinline__ int rank_target(int b) {
    if (b == 0) return 0;
    const float step = 500000.0f / 15.0f;   // float32-rounded, mimics jnp.linspace
    return (int)floorf((float)b * step);
}

__device__ __forceinline__ float wave_sum(float v) {
    #pragma unroll
    for (int o = 32; o; o >>= 1) v += __shfl_xor(v, o, 64);
    return v;
}

// Pass 1: row softmax of logits [N][C], write transposed probsT [C][N]
__global__ __launch_bounds__(256) void k_softmax_t(const float* __restrict__ logits,
                                                   float* __restrict__ probsT) {
    __shared__ float tile[64][101];
    __shared__ float red[256];
    __shared__ float mx[64];
    __shared__ float inv[64];
    const int row0 = blockIdx.x * 64;
    const int rows = min(64, NROWS - row0);
    const int t = threadIdx.x;
    const int total = rows * NCLS;
    for (int k = t; k < total; k += 256) {
        int r = k / NCLS, c = k - r * NCLS;
        tile[r][c] = logits[(size_t)(row0 + r) * NCLS + c];
    }
    __syncthreads();
    const int r = t >> 2, q = t & 3;   // 4 threads per row
    if (r < rows) {
        float m = -1e30f;
        #pragma unroll
        for (int c = 0; c < 25; ++c) m = fmaxf(m, tile[r][q * 25 + c]);
        red[t] = m;
    }
    __syncthreads();
    if (r < rows && q == 0)
        mx[r] = fmaxf(fmaxf(red[t], red[t + 1]), fmaxf(red[t + 2], red[t + 3]));
    __syncthreads();
    if (r < rows) {
        float m = mx[r], s = 0.f;
        #pragma unroll
        for (int c = 0; c < 25; ++c) {
            float e = __expf(tile[r][q * 25 + c] - m);
            tile[r][q * 25 + c] = e;
            s += e;
        }
        red[t] = s;
    }
    __syncthreads();
    if (r < rows && q == 0)
        inv[r] = 1.0f / (red[t] + red[t + 1] + red[t + 2] + red[t + 3]);
    __syncthreads();
    const int shift = (rows == 64) ? 4 : 3;
    const int gq = 1 << shift;
    const int ng = NCLS << shift;
    for (int k = t; k < ng; k += 256) {
        int c = k >> shift, g = k & (gq - 1);
        int rr = g << 2;
        float4 o;
        o.x = tile[rr + 0][c] * inv[rr + 0];
        o.y = tile[rr + 1][c] * inv[rr + 1];
        o.z = tile[rr + 2][c] * inv[rr + 2];
        o.w = tile[rr + 3][c] * inv[rr + 3];
        *(float4*)(probsT + (size_t)c * NROWS + row0 + rr) = o;
    }
}

// Pass 2: per-class L1 histogram (top 12 used float bits), 2 bank-rotated LDS
// copies, non-atomic flush to private copy per blockIdx.x
__global__ __launch_bounds__(256) void k_hist1(const float4* __restrict__ probsT4,
                                               int* __restrict__ hist1p) {
    __shared__ int h[2][4096];   // 32 KB
    const int c = blockIdx.y, t = threadIdx.x;
    int4* hz = (int4*)&h[0][0];
    for (int i = t; i < 2048; i += 256) hz[i] = make_int4(0, 0, 0, 0);
    __syncthreads();
    const int copy = t & 1;
    const int rot = copy << 4;
    const size_t base = (size_t)c * NROWS4;
    const int start = blockIdx.x * CH1;
    const int end = min(NROWS4, start + CH1);
    for (int i = start + t; i < end; i += 256) {
        float4 v = probsT4[base + i];
        atomicAdd(&h[copy][((__float_as_uint(v.x) >> 18) + rot) & 4095], 1);
        atomicAdd(&h[copy][((__float_as_uint(v.y) >> 18) + rot) & 4095], 1);
        atomicAdd(&h[copy][((__float_as_uint(v.z) >> 18) + rot) & 4095], 1);
        atomicAdd(&h[copy][((__float_as_uint(v.w) >> 18) + rot) & 4095], 1);
    }
    __syncthreads();
    int* out = hist1p + ((size_t)blockIdx.x * NCLS + c) * 4096;
    for (int i = t; i < 4096; i += 256)
        out[i] = h[0][i] + h[1][(i + 16) & 4095];
}

// Select L1 bucket per rank target; parallel prefix (shfl), dedupe via owner[];
// emit edgeArr = largest float strictly below the target bucket
__global__ __launch_bounds__(256) void k_sel1(const int* __restrict__ hist1p,
                                              int* __restrict__ tgt,
                                              int* __restrict__ below,
                                              int* __restrict__ owner,
                                              float* __restrict__ edgeArr) {
    __shared__ int wsum[4];
    __shared__ int stgt[NBINS];
    __shared__ int sbelow[NBINS];
    const int c = blockIdx.x, t = threadIdx.x;
    int4 acc[4] = {make_int4(0,0,0,0), make_int4(0,0,0,0),
                   make_int4(0,0,0,0), make_int4(0,0,0,0)};
    for (int k = 0; k < B1; ++k) {
        const int4* p = (const int4*)(hist1p + ((size_t)k * NCLS + c) * 4096) + t * 4;
        #pragma unroll
        for (int j = 0; j < 4; ++j) {
            int4 v = p[j];
            acc[j].x += v.x; acc[j].y += v.y; acc[j].z += v.z; acc[j].w += v.w;
        }
    }
    int loc[16];
    #pragma unroll
    for (int j = 0; j < 4; ++j) {
        loc[j * 4 + 0] = acc[j].x; loc[j * 4 + 1] = acc[j].y;
        loc[j * 4 + 2] = acc[j].z; loc[j * 4 + 3] = acc[j].w;
    }
    int s = 0;
    #pragma unroll
    for (int i = 0; i < 16; ++i) s += loc[i];
    // block-wide exclusive prefix of per-thread totals
    const int lane = t & 63, w = t >> 6;
    int incl = s;
    #pragma unroll
    for (int d = 1; d < 64; d <<= 1) {
        int n = __shfl_up(incl, d, 64);
        if (lane >= d) incl += n;
    }
    if (lane == 63) wsum[w] = incl;
    __syncthreads();
    int woff = 0;
    #pragma unroll
    for (int j = 0; j < 4; ++j) if (j < w) woff += wsum[j];
    const int cum0 = woff + incl - s;
    for (int b = 0; b < NBINS; ++b) {
        const int f = rank_target(b);
        int cc = cum0;
        #pragma unroll
        for (int i = 0; i < 16; ++i) {
            if (f >= cc && f < cc + loc[i]) { stgt[b] = t * 16 + i; sbelow[b] = cc; }
            cc += loc[i];
        }
    }
    __syncthreads();
    if (t == 0) {
        int ow = 0;
        for (int b = 0; b < NBINS; ++b) {
            if (b == 0 || stgt[b] != stgt[b - 1]) ow = b;
            owner[c * NBINS + b] = ow;
            tgt[c * NBINS + b] = stgt[b];
            below[c * NBINS + b] = sbelow[b];
            unsigned tg = (unsigned)stgt[b];
            edgeArr[c * NBINS + b] = tg ? __uint_as_float((tg << 18) - 1u) : 0.0f;
        }
    }
}

// Pass 3 (FUSED hist2+accum): one scan produces (a) per-target-bucket sub-hists
// {n, sum v, sum v^2} at 64 subs (flushed non-atomically to private copies) and
// (b) min-trick cumulative sums vs the L1 bucket low edge + class totals (accA).
// accA layout per class: [0..14]=sum min(v,edge_b), [15..29]=sum min^2, [30]=sumT, [31]=sumQ
__global__ __launch_bounds__(256) void k_scan2(const float4* __restrict__ probsT4,
                                               const int* __restrict__ tgt,
                                               const float* __restrict__ edgeArr,
                                               int* __restrict__ scan2p,
                                               float* __restrict__ accA) {
    __shared__ int stg[16];
    __shared__ int hn[HSZ];
    __shared__ float hT[HSZ];
    __shared__ float hQ[HSZ];
    __shared__ float lred[4][32];
    const int c = blockIdx.y, t = threadIdx.x;
    if (t < 16) stg[t] = (t < NBINS) ? tgt[c * NBINS + t] : 0x7FFFFFFF;
    for (int i = t; i < HSZ; i += 256) { hn[i] = 0; hT[i] = 0.f; hQ[i] = 0.f; }
    float edge[NBINS];
    #pragma unroll
    for (int b = 0; b < NBINS; ++b) edge[b] = edgeArr[c * NBINS + b];
    float mt[NBINS], mq[NBINS];
    #pragma unroll
    for (int b = 0; b < NBINS; ++b) { mt[b] = 0.f; mq[b] = 0.f; }
    float tT = 0.f, tQ = 0.f;
    __syncthreads();
    const size_t base = (size_t)c * NROWS4;
    const int start = blockIdx.x * CH2;
    const int end = min(NROWS4, start + CH2);
    for (int i = start + t; i < end; i += 256) {
        float4 v = probsT4[base + i];
        tT += (v.x + v.y) + (v.z + v.w);
        tQ = fmaf(v.x, v.x, fmaf(v.y, v.y, fmaf(v.z, v.z, fmaf(v.w, v.w, tQ))));
        #pragma unroll
        for (int b = 0; b < NBINS; ++b) {
            float m0 = fminf(v.x, edge[b]), m1 = fminf(v.y, edge[b]);
            float m2 = fminf(v.z, edge[b]), m3 = fminf(v.w, edge[b]);
            mt[b] += (m0 + m1) + (m2 + m3);
            mq[b] = fmaf(m0, m0, fmaf(m1, m1, fmaf(m2, m2, fmaf(m3, m3, mq[b]))));
        }
        float val[4] = {v.x, v.y, v.z, v.w};
        unsigned bx[4] = {__float_as_uint(v.x), __float_as_uint(v.y),
                          __float_as_uint(v.z), __float_as_uint(v.w)};
        #pragma unroll
        for (int e = 0; e < 4; ++e) {
            int k1 = (int)(bx[e] >> 18);
            int idx = 0;                      // lower_bound over sorted stg (dupes -> first slot)
            idx += (stg[idx + 7] < k1) ? 8 : 0;
            idx += (stg[idx + 3] < k1) ? 4 : 0;
            idx += (stg[idx + 1] < k1) ? 2 : 0;
            idx += (stg[idx] < k1) ? 1 : 0;
            if (idx < NBINS && stg[idx] == k1) {
                int sub = idx * NSUB + ((bx[e] >> 12) & (NSUB - 1));
                atomicAdd(&hn[sub], 1);
                atomicAdd(&hT[sub], val[e]);
                atomicAdd(&hQ[sub], val[e] * val[e]);
            }
        }
    }
    __syncthreads();
    // flush private copy: [blk*NCLS+c][3][960]
    int* on = scan2p + ((size_t)(blockIdx.x * NCLS + c) * 3) * HSZ;
    float* oT = (float*)(on + HSZ);
    float* oQ = (float*)(on + 2 * HSZ);
    for (int i = t; i < HSZ; i += 256) { on[i] = hn[i]; oT[i] = hT[i]; oQ[i] = hQ[i]; }
    // reduce register accumulators into accA
    const int w = t >> 6, lane = t & 63;
    float vals[32];
    #pragma unroll
    for (int b = 0; b < NBINS; ++b) { vals[b] = mt[b]; vals[NBINS + b] = mq[b]; }
    vals[30] = tT; vals[31] = tQ;
    #pragma unroll
    for (int j = 0; j < 32; ++j) vals[j] = wave_sum(vals[j]);
    if (lane == 0) {
        #pragma unroll
        for (int j = 0; j < 32; ++j) lred[w][j] = vals[j];
    }
    __syncthreads();
    if (t < 32) {
        float s = lred[0][t] + lred[1][t] + lred[2][t] + lred[3][t];
        atomicAdd(&accA[c * 32 + t], s);
    }
}

// Select sub-bucket (single wave, shfl prefix over 64 subs); assemble exact
// cumulative {N, T, Q} at the boundary in double
__global__ __launch_bounds__(64) void k_sel2(const int* __restrict__ scan2p,
                                             const int* __restrict__ tgt,
                                             const int* __restrict__ below,
                                             const int* __restrict__ owner,
                                             const float* __restrict__ edgeArr,
                                             const float* __restrict__ accA,
                                             float* __restrict__ bounds,
                                             int* __restrict__ cumN,
                                             double* __restrict__ cumT,
                                             double* __restrict__ cumQ) {
    const int b = blockIdx.x, c = blockIdx.y, t = threadIdx.x;   // t < 64
    const int ow = owner[c * NBINS + b];
    int nj = 0; float Tj = 0.f, Qj = 0.f;
    for (int k = 0; k < B2; ++k) {
        const int* p = scan2p + ((size_t)(k * NCLS + c) * 3) * HSZ + ow * NSUB + t;
        nj += p[0];
        Tj += ((const float*)p)[HSZ];
        Qj += ((const float*)p)[2 * HSZ];
    }
    const int own = nj;
    #pragma unroll
    for (int d = 1; d < 64; d <<= 1) {
        int nn = __shfl_up(nj, d, 64);
        float TT = __shfl_up(Tj, d, 64);
        float QQ = __shfl_up(Qj, d, 64);
        if (t >= d) { nj += nn; Tj += TT; Qj += QQ; }
    }
    const int bel = below[c * NBINS + b];
    const int lr = rank_target(b) - bel;
    if (lr >= nj - own && lr < nj) {
        unsigned bits = ((unsigned)tgt[c * NBINS + b] << 18) | ((unsigned)t << 12) | 0xFFFu;
        bounds[c * NBINS + b] = __uint_as_float(bits);
        cumN[c * NBINS + b] = bel + nj;
        double edge = (double)edgeArr[c * NBINS + b];
        double above = (double)(NROWS - bel);
        cumT[c * NBINS + b] = ((double)accA[c * 32 + b] - edge * above) + (double)Tj;
        cumQ[c * NBINS + b] = ((double)accA[c * 32 + NBINS + b] - edge * edge * above) + (double)Qj;
    }
}

// Pass 4: label correction — only elements with lab=1 (their label's class)
__global__ __launch_bounds__(256) void k_label(const float* __restrict__ probsT,
                                               const int* __restrict__ labels,
                                               const float* __restrict__ bounds,
                                               float* __restrict__ accLab) {
    const int n = blockIdx.x * 256 + threadIdx.x;
    if (n >= NROWS) return;
    const int c = labels[n];
    const float conf = probsT[(size_t)c * NROWS + n];
    const float* bd = bounds + c * NBINS;
    if (conf > bd[0]) {
        int idx = 0;
        #pragma unroll
        for (int b = 1; b < NBINS; ++b) idx += (conf > bd[b]) ? 1 : 0;
        atomicAdd(&accLab[(c * NBINS + idx) * 2 + 0], 1.0f);
        atomicAdd(&accLab[(c * NBINS + idx) * 2 + 1], conf);
    }
}

// Pass 5: closed-form LOO combine in double
__global__ __launch_bounds__(256) void k_final(const float* __restrict__ accA,
                                               const int* __restrict__ cumN,
                                               const double* __restrict__ cumT,
                                               const double* __restrict__ cumQ,
                                               const float* __restrict__ accLab,
                                               float* __restrict__ out) {
    __shared__ double red[256];
    const int t = threadIdx.x;
    double local = 0.0;
    for (int k = t; k < NCLS * NBINS; k += 256) {
        int c = k / NBINS, b = k - c * NBINS;
        double n, T, Q;
        if (b < NBINS - 1) {
            n = (double)(cumN[k + 1] - cumN[k]);
            T = cumT[k + 1] - cumT[k];
            Q = cumQ[k + 1] - cumQ[k];
        } else {
            n = (double)(NROWS - cumN[k]);
            T = (double)accA[c * 32 + 30] - cumT[k];
            Q = (double)accA[c * 32 + 31] - cumQ[k];
        }
        double S = accLab[k * 2 + 0], T1 = accLab[k * 2 + 1];
        if (n > 1.5) {
            double inv = 1.0 / (n - 1.0);
            double a0 = S * inv, a1 = (S - 1.0) * inv;
            local += Q - 2.0 * a0 * T + 2.0 * T1 * inv + (n - S) * a0 * a0 + S * a1 * a1;
        }
    }
    red[t] = local;
    __syncthreads();
    for (int s = 128; s; s >>= 1) {
        if (t < s) red[t] += red[t + s];
        __syncthreads();
    }
    if (t == 0) out[0] = (float)(red[0] / ((double)NROWS * (double)NCLS));
}

extern "C" void kernel_launch(void* const* d_in, const int* in_sizes, int n_in,
                              void* d_out, int out_size, void* d_ws, size_t ws_size,
                              hipStream_t stream) {
    const float* logits = (const float*)d_in[0];
    const int* labels = (const int*)d_in[1];
    float* out = (float*)d_out;
    char* ws = (char*)d_ws;
    size_t off = 0;
    auto alloc = [&](size_t bytes) -> void* {
        off = (off + 255) & ~(size_t)255;
        void* p = ws + off;
        off += bytes;
        return p;
    };
    float* probsT = (float*)alloc((size_t)NCLS * NROWS * 4);               // 200 MB
    // shared region: hist1p (hist1->sel1) then reused as scan2p (scan2->sel2)
    size_t h1bytes = (size_t)B1 * NCLS * 4096 * 4;                         // 22.9 MB
    size_t s2bytes = (size_t)B2 * NCLS * 3 * HSZ * 4;                      // 18.4 MB
    int* hist1p = (int*)alloc(h1bytes > s2bytes ? h1bytes : s2bytes);
    int* scan2p = hist1p;
    // --- zeroed region (contiguous, single small memset) ---
    char* zbase = ws + ((off + 255) & ~(size_t)255);
    float* accA   = (float*)alloc((size_t)NCLS * 32 * 4);
    float* accLab = (float*)alloc((size_t)NCLS * NBINS * 2 * 4);
    size_t zlen = (size_t)((ws + off) - zbase);
    // --- written-before-read region ---
    int*    tgt     = (int*)alloc((size_t)NCLS * NBINS * 4);
    int*    below   = (int*)alloc((size_t)NCLS * NBINS * 4);
    int*    owner   = (int*)alloc((size_t)NCLS * NBINS * 4);
    float*  edgeArr = (float*)alloc((size_t)NCLS * NBINS * 4);
    float*  bounds  = (float*)alloc((size_t)NCLS * NBINS * 4);
    int*    cumN    = (int*)alloc((size_t)NCLS * NBINS * 4);
    double* cumT    = (double*)alloc((size_t)NCLS * NBINS * 8);
    double* cumQ    = (double*)alloc((size_t)NCLS * NBINS * 8);
    if (off > ws_size) {
        hipMemsetAsync(d_out, 0xFF, 4, stream);   // NaN sentinel
        return;
    }
    hipMemsetAsync(zbase, 0, zlen, stream);

    k_softmax_t<<<(NROWS + 63) / 64, 256, 0, stream>>>(logits, probsT);
    k_hist1<<<dim3(B1, NCLS), 256, 0, stream>>>((const float4*)probsT, hist1p);
    k_sel1<<<NCLS, 256, 0, stream>>>(hist1p, tgt, below, owner, edgeArr);
    k_scan2<<<dim3(B2, NCLS), 256, 0, stream>>>((const float4*)probsT, tgt, edgeArr,
                                                scan2p, accA);
    k_sel2<<<dim3(NBINS, NCLS), 64, 0, stream>>>(scan2p, tgt, below, owner, edgeArr,
                                                 accA, bounds, cumN, cumT, cumQ);
    k_label<<<(NROWS + 255) / 256, 256, 0, stream>>>(probsT, labels, bounds, accLab);
    k_final<<<1, 256, 0, stream>>>(accA, cumN, cumT, cumQ, accLab, out);
}